// Round 4
// baseline (51475.519 us; speedup 1.0000x reference)
//
#include <hip/hip_runtime.h>
#include <stdint.h>

#define T_STEPS 512
#define BATCH   16
#define CD      1024
#define GD      4096          // 4*CD
#define ID      320
#define HD      1024
#define MROWS   (BATCH*T_STEPS)   // 8192

typedef short bf16x8 __attribute__((ext_vector_type(8)));
typedef float f32x4  __attribute__((ext_vector_type(4)));
typedef unsigned short u16;

__device__ __forceinline__ u16 f2bf(float f) {
  union { float f; uint32_t u; } v; v.f = f;
  uint32_t r = v.u + 0x7FFFu + ((v.u >> 16) & 1u);
  return (u16)(r >> 16);
}
__device__ __forceinline__ float bf2f(u16 u) {
  union { uint32_t u; float f; } v; v.u = ((uint32_t)u) << 16;
  return v.f;
}
__device__ __forceinline__ float sigm(float x) { return 1.0f / (1.0f + __expf(-x)); }

// ---------------------------------------------------------------------------
// Tiled bf16-MFMA GEMM: Out[m,n] = sum_k A[m,k]*B[n,k] + bias1[n](+bias2[n])
// A: [MROWS,K] (f32 or bf16), B: [N,K] f32 (converted to bf16 in staging).
// ---------------------------------------------------------------------------
template<int K, bool A_BF16, bool MASK_A, bool TANH_OUT, bool OUT_BF16>
__global__ __launch_bounds__(256)
void gemm64(const void* __restrict__ Av, const float* __restrict__ B,
            const float* __restrict__ bias1, const float* __restrict__ bias2,
            void* __restrict__ Outv, const int* __restrict__ ilens, int N) {
  const int m0 = blockIdx.x * 64;
  const int n0 = blockIdx.y * 64;
  const int tid = threadIdx.x;
  const int lane = tid & 63, wid = tid >> 6;
  const int wm = wid >> 1, wn = wid & 1;
  __shared__ u16 As[64][72];
  __shared__ u16 Bs[64][72];
  f32x4 acc[2][2];
  #pragma unroll
  for (int i = 0; i < 2; i++)
    #pragma unroll
    for (int j = 0; j < 2; j++) acc[i][j] = (f32x4){0.f,0.f,0.f,0.f};

  for (int k0 = 0; k0 < K; k0 += 64) {
    if constexpr (A_BF16) {
      const u16* A = (const u16*)Av;
      #pragma unroll
      for (int i = 0; i < 2; i++) {
        int idx = tid + i * 256;              // 0..511
        int row = idx >> 3, c8 = (idx & 7) * 8;
        int m = m0 + row;
        bf16x8 v = *(const bf16x8*)(A + (size_t)m * K + k0 + c8);
        if constexpr (MASK_A) {
          int tt = m & (T_STEPS - 1), b = m >> 9;
          if (tt >= ilens[b]) v = (bf16x8){0,0,0,0,0,0,0,0};
        }
        *(bf16x8*)&As[row][c8] = v;
      }
    } else {
      const float* A = (const float*)Av;
      #pragma unroll
      for (int i = 0; i < 4; i++) {
        int idx = tid + i * 256;              // 0..1023
        int row = idx >> 4, c4 = (idx & 15) * 4;
        const float4 v = *(const float4*)(A + (size_t)(m0 + row) * K + k0 + c4);
        As[row][c4+0] = f2bf(v.x); As[row][c4+1] = f2bf(v.y);
        As[row][c4+2] = f2bf(v.z); As[row][c4+3] = f2bf(v.w);
      }
    }
    #pragma unroll
    for (int i = 0; i < 4; i++) {
      int idx = tid + i * 256;
      int row = idx >> 4, c4 = (idx & 15) * 4;
      const float4 v = *(const float4*)(B + (size_t)(n0 + row) * K + k0 + c4);
      Bs[row][c4+0] = f2bf(v.x); Bs[row][c4+1] = f2bf(v.y);
      Bs[row][c4+2] = f2bf(v.z); Bs[row][c4+3] = f2bf(v.w);
    }
    __syncthreads();
    const int rl = lane & 15;
    #pragma unroll
    for (int kk = 0; kk < 64; kk += 32) {
      const int kg = (lane >> 4) * 8 + kk;
      bf16x8 a[2], b[2];
      #pragma unroll
      for (int i = 0; i < 2; i++) a[i] = *(const bf16x8*)&As[wm*32 + i*16 + rl][kg];
      #pragma unroll
      for (int j = 0; j < 2; j++) b[j] = *(const bf16x8*)&Bs[wn*32 + j*16 + rl][kg];
      #pragma unroll
      for (int i = 0; i < 2; i++)
        #pragma unroll
        for (int j = 0; j < 2; j++)
          acc[i][j] = __builtin_amdgcn_mfma_f32_16x16x32_bf16(a[i], b[j], acc[i][j], 0, 0, 0);
    }
    __syncthreads();
  }
  // epilogue: D row=(lane>>4)*4+r (m), col=lane&15 (n)   [m89/m91-verified layout]
  const int rl = lane & 15, rg = lane >> 4;
  #pragma unroll
  for (int i = 0; i < 2; i++)
    #pragma unroll
    for (int j = 0; j < 2; j++) {
      int n = n0 + wn*32 + j*16 + rl;
      float bs = (bias1 ? bias1[n] : 0.f) + (bias2 ? bias2[n] : 0.f);
      #pragma unroll
      for (int r = 0; r < 4; r++) {
        int m = m0 + wm*32 + i*16 + rg*4 + r;
        float v = acc[i][j][r] + bs;
        if constexpr (TANH_OUT) v = tanhf(v);
        if constexpr (OUT_BF16) ((u16*)Outv)[(size_t)m * N + n] = f2bf(v);
        else                    ((float*)Outv)[(size_t)m * N + n] = v;
      }
    }
}

// ---------------------------------------------------------------------------
// All-to-all grid barrier: every wg stores its flag (release), then every
// wg's 64 lanes poll all 256 flags directly (4 per lane, acquire). Removes
// the master-wg gather+release round-trip of the classic 2-phase barrier.
// Monotonic step counter => re-entrant, no reset. 256 single-wave wgs.
// ---------------------------------------------------------------------------
__device__ __forceinline__ void gbar(int* flags, int tgt, int wg, int lane) {
  __threadfence();   // drain h/YS stores before arrival flag
  if (lane == 0)
    __hip_atomic_store(&flags[wg * 16], tgt, __ATOMIC_RELEASE, __HIP_MEMORY_SCOPE_AGENT);
  #pragma unroll
  for (int base = 0; base < 256; base += 64) {
    int w = base + lane;
    while (__hip_atomic_load(&flags[w * 16], __ATOMIC_ACQUIRE, __HIP_MEMORY_SCOPE_AGENT) < tgt)
      __builtin_amdgcn_s_sleep(1);
  }
  __syncthreads();
}

// ---------------------------------------------------------------------------
// Persistent LSTM recurrence for one layer.
// 256 wgs x 64 threads. wg owns channels ch0..ch0+3 -> 16 gate rows
// (i0..3,f0..3,g0..3,o0..3) staged to LDS as bf16. One grid barrier per step.
// ---------------------------------------------------------------------------
__global__ __launch_bounds__(64)
void rec_kernel(const u16* __restrict__ XG, const float* __restrict__ Whh,
                u16* __restrict__ YS, u16* __restrict__ hbuf,
                int* flags) {
  const int wg = blockIdx.x;       // 0..255
  const int lane = threadIdx.x;    // 0..63
  const int ch0 = wg * 4;
  __shared__ u16 Ws[16][1032];     // 16 gate rows x K=1024 (+pad: 2-way banks)
  __shared__ float P[16][20];      // [batch][gate-row]

  // stage W_hh slice (f32 -> bf16)
  for (int r = 0; r < 16; r++) {
    const float* src = Whh + (size_t)((r >> 2) * CD + ch0 + (r & 3)) * CD;
    for (int c = lane * 4; c < CD; c += 256) {
      float4 v = *(const float4*)(src + c);
      Ws[r][c+0] = f2bf(v.x); Ws[r][c+1] = f2bf(v.y);
      Ws[r][c+2] = f2bf(v.z); Ws[r][c+3] = f2bf(v.w);
    }
  }
  __syncthreads();

  const int b_ = lane >> 2, ch_ = lane & 3;        // elementwise owner (16b x 4ch)
  const int rl = lane & 15, kg8 = (lane >> 4) * 8; // MFMA fragment lane coords
  const size_t xg_base = ((size_t)b_ * T_STEPS) * GD + ch0 + ch_;
  float c_state = 0.f;

  // prefetch xg(t=0)
  float xn0, xn1, xn2, xn3;
  {
    const u16* p = XG + xg_base;
    xn0 = bf2f(p[0]); xn1 = bf2f(p[CD]); xn2 = bf2f(p[2*CD]); xn3 = bf2f(p[3*CD]);
  }

  int cur = 0;
  for (int t = 0; t < T_STEPS; t++) {
    // P[b][row16] = h_prev @ Ws^T  via 32 chained 16x16x32 MFMAs (2 indep chains)
    const u16* hrow = hbuf + cur * (BATCH * CD) + rl * CD + kg8;
    f32x4 acc0 = (f32x4){0.f,0.f,0.f,0.f}, acc1 = (f32x4){0.f,0.f,0.f,0.f};
    #pragma unroll
    for (int ks = 0; ks < 32; ks += 2) {
      bf16x8 a0 = *(const bf16x8*)(hrow + ks * 32);
      bf16x8 b0 = *(const bf16x8*)&Ws[rl][ks * 32 + kg8];
      acc0 = __builtin_amdgcn_mfma_f32_16x16x32_bf16(a0, b0, acc0, 0, 0, 0);
      bf16x8 a1 = *(const bf16x8*)(hrow + ks * 32 + 32);
      bf16x8 b1 = *(const bf16x8*)&Ws[rl][(ks + 1) * 32 + kg8];
      acc1 = __builtin_amdgcn_mfma_f32_16x16x32_bf16(a1, b1, acc1, 0, 0, 0);
    }
    f32x4 acc = acc0 + acc1;
    #pragma unroll
    for (int r = 0; r < 4; r++) P[(lane >> 4) * 4 + r][rl] = acc[r];
    __syncthreads();

    float gi = xn0 + P[b_][0 + ch_];
    float gf = xn1 + P[b_][4 + ch_];
    float gg = xn2 + P[b_][8 + ch_];
    float go_ = xn3 + P[b_][12 + ch_];

    if (t + 1 < T_STEPS) {  // prefetch next xg (hidden behind barrier latency)
      const u16* p = XG + xg_base + (size_t)(t + 1) * GD;
      xn0 = bf2f(p[0]); xn1 = bf2f(p[CD]); xn2 = bf2f(p[2*CD]); xn3 = bf2f(p[3*CD]);
    }

    c_state = sigm(gf) * c_state + sigm(gi) * tanhf(gg);
    float hv = sigm(go_) * tanhf(c_state);
    u16 hb = f2bf(hv);
    hbuf[(cur ^ 1) * (BATCH * CD) + b_ * CD + ch0 + ch_] = hb;
    YS[((size_t)b_ * T_STEPS + t) * CD + ch0 + ch_] = hb;

    __syncthreads();           // P reads done before next iter's writes
    gbar(flags, t + 1, wg, lane);
    cur ^= 1;
  }
}

__global__ void write_ilens_kernel(float* out, const int* ilens) {
  if (threadIdx.x < BATCH)
    out[(size_t)MROWS * HD + threadIdx.x] = (float)ilens[threadIdx.x];
}

// ---------------------------------------------------------------------------
extern "C" void kernel_launch(void* const* d_in, const int* in_sizes, int n_in,
                              void* d_out, int out_size, void* d_ws, size_t ws_size,
                              hipStream_t stream) {
  const float* xpad   = (const float*)d_in[0];
  const float* W_ih0  = (const float*)d_in[1];
  const float* W_ihr  = (const float*)d_in[2];
  const float* W_hh   = (const float*)d_in[3];
  const float* b_ih   = (const float*)d_in[4];
  const float* b_hh   = (const float*)d_in[5];
  const float* W_last = (const float*)d_in[6];
  const float* b_last = (const float*)d_in[7];
  const int*   ilens  = (const int*)d_in[8];

  char* ws = (char*)d_ws;
  u16* XG    = (u16*)(ws);                    // 16*512*4096 bf16 = 67,108,864 B
  u16* YS0   = (u16*)(ws + 67108864);         // 16,777,216 B
  u16* YS1   = (u16*)(ws + 83886080);         // 16,777,216 B
  u16* hbuf  = (u16*)(ws + 100663296);        // 2*16*1024 bf16 = 65,536 B
  int* flags = (int*)(ws + 100728832);        // 256*16 ints = 16,384 B
  const size_t barrier_bytes = 65536 + 16384; // hbuf+flags contiguous

  float* out = (float*)d_out;

  dim3 blk(256);
  dim3 gXG(MROWS / 64, GD / 64);
  dim3 gFin(MROWS / 64, HD / 64);

  // ---- layer 0 ----
  gemm64<ID, false, false, false, true><<<gXG, blk, 0, stream>>>(
      xpad, W_ih0, b_ih, b_hh, XG, nullptr, GD);
  hipMemsetAsync(hbuf, 0, barrier_bytes, stream);
  rec_kernel<<<dim3(256), dim3(64), 0, stream>>>(XG, W_hh, YS0, hbuf, flags);

  // ---- layer 1 ----
  gemm64<CD, true, false, false, true><<<gXG, blk, 0, stream>>>(
      YS0, W_ihr, b_ih + GD, b_hh + GD, XG, nullptr, GD);
  hipMemsetAsync(hbuf, 0, barrier_bytes, stream);
  rec_kernel<<<dim3(256), dim3(64), 0, stream>>>(
      XG, W_hh + (size_t)GD * CD, YS1, hbuf, flags);

  // ---- layer 2 ----
  gemm64<CD, true, false, false, true><<<gXG, blk, 0, stream>>>(
      YS1, W_ihr + (size_t)GD * CD, b_ih + 2 * GD, b_hh + 2 * GD, XG, nullptr, GD);
  hipMemsetAsync(hbuf, 0, barrier_bytes, stream);
  rec_kernel<<<dim3(256), dim3(64), 0, stream>>>(
      XG, W_hh + 2 * (size_t)GD * CD, YS0, hbuf, flags);

  // ---- layer 3 ----
  gemm64<CD, true, false, false, true><<<gXG, blk, 0, stream>>>(
      YS0, W_ihr + 2 * (size_t)GD * CD, b_ih + 3 * GD, b_hh + 3 * GD, XG, nullptr, GD);
  hipMemsetAsync(hbuf, 0, barrier_bytes, stream);
  rec_kernel<<<dim3(256), dim3(64), 0, stream>>>(
      XG, W_hh + 3 * (size_t)GD * CD, YS1, hbuf, flags);

  // ---- masked tanh projection + ilens ----
  gemm64<CD, true, true, true, false><<<gFin, blk, 0, stream>>>(
      YS1, W_last, b_last, nullptr, out, ilens, HD);
  write_ilens_kernel<<<dim3(1), dim3(64), 0, stream>>>(out, ilens);
}

// Round 6
// 23520.071 us; speedup vs baseline: 2.1886x; 2.1886x over previous
//
#include <hip/hip_runtime.h>
#include <stdint.h>

#define T_STEPS 512
#define BATCH   16
#define CD      1024
#define GD      4096          // 4*CD
#define ID      320
#define HD      1024
#define MROWS   (BATCH*T_STEPS)   // 8192
#define NWG     64            // recurrence grid size
#define CPW     16            // channels per wg

typedef short bf16x8 __attribute__((ext_vector_type(8)));
typedef float f32x4  __attribute__((ext_vector_type(4)));
typedef unsigned short u16;
typedef unsigned long long u64;

__device__ __forceinline__ u16 f2bf(float f) {
  union { float f; uint32_t u; } v; v.f = f;
  uint32_t r = v.u + 0x7FFFu + ((v.u >> 16) & 1u);
  return (u16)(r >> 16);
}
__device__ __forceinline__ float bf2f(u16 u) {
  union { uint32_t u; float f; } v; v.u = ((uint32_t)u) << 16;
  return v.f;
}
__device__ __forceinline__ float sigm(float x) { return 1.0f / (1.0f + __expf(-x)); }

// ---------------------------------------------------------------------------
// Tiled bf16-MFMA GEMM (unchanged — verified passing in round 4).
// ---------------------------------------------------------------------------
template<int K, bool A_BF16, bool MASK_A, bool TANH_OUT, bool OUT_BF16>
__global__ __launch_bounds__(256)
void gemm64(const void* __restrict__ Av, const float* __restrict__ B,
            const float* __restrict__ bias1, const float* __restrict__ bias2,
            void* __restrict__ Outv, const int* __restrict__ ilens, int N) {
  const int m0 = blockIdx.x * 64;
  const int n0 = blockIdx.y * 64;
  const int tid = threadIdx.x;
  const int lane = tid & 63, wid = tid >> 6;
  const int wm = wid >> 1, wn = wid & 1;
  __shared__ u16 As[64][72];
  __shared__ u16 Bs[64][72];
  f32x4 acc[2][2];
  #pragma unroll
  for (int i = 0; i < 2; i++)
    #pragma unroll
    for (int j = 0; j < 2; j++) acc[i][j] = (f32x4){0.f,0.f,0.f,0.f};

  for (int k0 = 0; k0 < K; k0 += 64) {
    if constexpr (A_BF16) {
      const u16* A = (const u16*)Av;
      #pragma unroll
      for (int i = 0; i < 2; i++) {
        int idx = tid + i * 256;
        int row = idx >> 3, c8 = (idx & 7) * 8;
        int m = m0 + row;
        bf16x8 v = *(const bf16x8*)(A + (size_t)m * K + k0 + c8);
        if constexpr (MASK_A) {
          int tt = m & (T_STEPS - 1), b = m >> 9;
          if (tt >= ilens[b]) v = (bf16x8){0,0,0,0,0,0,0,0};
        }
        *(bf16x8*)&As[row][c8] = v;
      }
    } else {
      const float* A = (const float*)Av;
      #pragma unroll
      for (int i = 0; i < 4; i++) {
        int idx = tid + i * 256;
        int row = idx >> 4, c4 = (idx & 15) * 4;
        const float4 v = *(const float4*)(A + (size_t)(m0 + row) * K + k0 + c4);
        As[row][c4+0] = f2bf(v.x); As[row][c4+1] = f2bf(v.y);
        As[row][c4+2] = f2bf(v.z); As[row][c4+3] = f2bf(v.w);
      }
    }
    #pragma unroll
    for (int i = 0; i < 4; i++) {
      int idx = tid + i * 256;
      int row = idx >> 4, c4 = (idx & 15) * 4;
      const float4 v = *(const float4*)(B + (size_t)(n0 + row) * K + k0 + c4);
      Bs[row][c4+0] = f2bf(v.x); Bs[row][c4+1] = f2bf(v.y);
      Bs[row][c4+2] = f2bf(v.z); Bs[row][c4+3] = f2bf(v.w);
    }
    __syncthreads();
    const int rl = lane & 15;
    #pragma unroll
    for (int kk = 0; kk < 64; kk += 32) {
      const int kg = (lane >> 4) * 8 + kk;
      bf16x8 a[2], b[2];
      #pragma unroll
      for (int i = 0; i < 2; i++) a[i] = *(const bf16x8*)&As[wm*32 + i*16 + rl][kg];
      #pragma unroll
      for (int j = 0; j < 2; j++) b[j] = *(const bf16x8*)&Bs[wn*32 + j*16 + rl][kg];
      #pragma unroll
      for (int i = 0; i < 2; i++)
        #pragma unroll
        for (int j = 0; j < 2; j++)
          acc[i][j] = __builtin_amdgcn_mfma_f32_16x16x32_bf16(a[i], b[j], acc[i][j], 0, 0, 0);
    }
    __syncthreads();
  }
  const int rl = lane & 15, rg = lane >> 4;
  #pragma unroll
  for (int i = 0; i < 2; i++)
    #pragma unroll
    for (int j = 0; j < 2; j++) {
      int n = n0 + wn*32 + j*16 + rl;
      float bs = (bias1 ? bias1[n] : 0.f) + (bias2 ? bias2[n] : 0.f);
      #pragma unroll
      for (int r = 0; r < 4; r++) {
        int m = m0 + wm*32 + i*16 + rg*4 + r;
        float v = acc[i][j][r] + bs;
        if constexpr (TANH_OUT) v = tanhf(v);
        if constexpr (OUT_BF16) ((u16*)Outv)[(size_t)m * N + n] = f2bf(v);
        else                    ((float*)Outv)[(size_t)m * N + n] = v;
      }
    }
}

// ---------------------------------------------------------------------------
// Persistent LSTM recurrence, v2: 64 wgs x 256 threads (4 waves).
// wg owns 16 channels -> 64 gate rows; wave g computes gate g's 16 rows.
// W_hh slice in LDS (128 KB, XOR-swizzled). h exchanged via RELAXED AGENT
// atomics (coherence-point path) -- no threadfence, no acquire-invalidate.
// Barrier: 64 flags, wave 0 lane l polls wg l. One release store per wg/step.
// ---------------------------------------------------------------------------
__global__ __launch_bounds__(256)
void rec_kernel(const u16* __restrict__ XG, const float* __restrict__ Whh,
                u16* __restrict__ YS, u16* hbuf, int* flags) {
  const int wg  = blockIdx.x;        // 0..63
  const int tid = threadIdx.x;       // 0..255
  const int lane = tid & 63;
  const int g    = tid >> 6;         // wave index = gate index
  const int ch0  = wg * CPW;

  __shared__ u16  Ws[64][1024];      // elem c of row r stored at c ^ ((r&7)<<3)
  __shared__ float P[64][17];        // P[gate*16+ch][b]
  __shared__ u16  Hpack[16][16];     // h bf16 [b][ch]

  // ---- stage W_hh slice (f32 -> bf16, swizzled) ----
  for (int idx = tid; idx < 64 * 256; idx += 256) {
    int r  = idx >> 8;               // 0..63 : gate r>>4, channel r&15
    int c4 = (idx & 255) * 4;
    const float* src = Whh + ((size_t)(r >> 4) * CD + ch0 + (r & 15)) * CD + c4;
    float4 v = *(const float4*)src;
    int cs = c4 ^ ((r & 7) << 3);    // XOR bits 3..5: 16B-granular swizzle
    Ws[r][cs+0] = f2bf(v.x); Ws[r][cs+1] = f2bf(v.y);
    Ws[r][cs+2] = f2bf(v.z); Ws[r][cs+3] = f2bf(v.w);
  }
  __syncthreads();

  const int rm  = lane & 15;                 // A-row within wave tile / B-col (b)
  const int kg8 = (lane >> 4) * 8;           // k-group
  const int xk  = (rm & 7) << 3;             // per-lane swizzle key
  const int b_  = tid >> 4, c_ = tid & 15;   // elementwise owner (b, ch)
  float c_state = 0.f;

  // xg prefetch (t=0): gates at stride CD, 16 contiguous ch per wg -> 32B/(b,g)
  const u16* xgp = XG + ((size_t)b_ * T_STEPS) * GD + ch0 + c_;
  float xn0 = bf2f(xgp[0]), xn1 = bf2f(xgp[CD]),
        xn2 = bf2f(xgp[2*CD]), xn3 = bf2f(xgp[3*CD]);

  int cur = 0;
  for (int t = 0; t < T_STEPS; ++t) {
    // ---- P[r][b] = sum_k W[r][k] * h[b][k] : 32 MFMAs, 2 indep chains ----
    const u64* hb = (const u64*)(hbuf + (size_t)cur * (BATCH*CD)) + (rm * CD + kg8) / 4;
    f32x4 acc0 = (f32x4){0.f,0.f,0.f,0.f}, acc1 = (f32x4){0.f,0.f,0.f,0.f};
    #pragma unroll
    for (int ks = 0; ks < 32; ks += 2) {
      union { u64 q[2]; bf16x8 v; } b0, b1;
      b0.q[0] = __hip_atomic_load(hb + ks*8,     __ATOMIC_RELAXED, __HIP_MEMORY_SCOPE_AGENT);
      b0.q[1] = __hip_atomic_load(hb + ks*8 + 1, __ATOMIC_RELAXED, __HIP_MEMORY_SCOPE_AGENT);
      b1.q[0] = __hip_atomic_load(hb + ks*8 + 8, __ATOMIC_RELAXED, __HIP_MEMORY_SCOPE_AGENT);
      b1.q[1] = __hip_atomic_load(hb + ks*8 + 9, __ATOMIC_RELAXED, __HIP_MEMORY_SCOPE_AGENT);
      bf16x8 a0 = *(const bf16x8*)&Ws[(g<<4)+rm][(ks*32 + kg8) ^ xk];
      bf16x8 a1 = *(const bf16x8*)&Ws[(g<<4)+rm][((ks+1)*32 + kg8) ^ xk];
      acc0 = __builtin_amdgcn_mfma_f32_16x16x32_bf16(a0, b0.v, acc0, 0, 0, 0);
      acc1 = __builtin_amdgcn_mfma_f32_16x16x32_bf16(a1, b1.v, acc1, 0, 0, 0);
    }
    f32x4 acc = acc0 + acc1;
    #pragma unroll
    for (int r4 = 0; r4 < 4; ++r4)
      P[(g << 4) + ((lane >> 4) << 2) + r4][rm] = acc[r4];
    __syncthreads();

    // ---- gates + state update (thread owns (b_, c_)) ----
    float gi = xn0 + P[c_][b_];
    float gf = xn1 + P[16 + c_][b_];
    float gg = xn2 + P[32 + c_][b_];
    float go = xn3 + P[48 + c_][b_];
    if (t + 1 < T_STEPS) {
      const u16* p = xgp + (size_t)(t + 1) * GD;
      xn0 = bf2f(p[0]); xn1 = bf2f(p[CD]); xn2 = bf2f(p[2*CD]); xn3 = bf2f(p[3*CD]);
    }
    c_state = sigm(gf) * c_state + sigm(gi) * tanhf(gg);
    float hv = sigm(go) * tanhf(c_state);
    Hpack[b_][c_] = f2bf(hv);
    __syncthreads();

    // ---- wave 0: publish h (write-through), YS, flag release, poll ----
    if (tid < 64) {
      int bb = tid >> 2, q = tid & 3;
      u64 hw = *(const u64*)&Hpack[bb][q * 4];
      __hip_atomic_store((u64*)(hbuf + (size_t)(cur ^ 1) * (BATCH*CD) + bb * CD + ch0 + q * 4),
                         hw, __ATOMIC_RELAXED, __HIP_MEMORY_SCOPE_AGENT);
      *(u64*)(YS + ((size_t)bb * T_STEPS + t) * CD + ch0 + q * 4) = hw;
      if (t + 1 < T_STEPS) {
        if (tid == 0)   // release: wave-wide vmcnt(0) drain precedes flag store
          __hip_atomic_store(&flags[wg * 16], t + 1, __ATOMIC_RELEASE, __HIP_MEMORY_SCOPE_AGENT);
        while (__hip_atomic_load(&flags[tid * 16], __ATOMIC_RELAXED, __HIP_MEMORY_SCOPE_AGENT) < t + 1)
          __builtin_amdgcn_s_sleep(1);
        asm volatile("" ::: "memory");
      }
    }
    __syncthreads();
    cur ^= 1;
  }
}

__global__ void write_ilens_kernel(float* out, const int* ilens) {
  if (threadIdx.x < BATCH)
    out[(size_t)MROWS * HD + threadIdx.x] = (float)ilens[threadIdx.x];
}

// ---------------------------------------------------------------------------
extern "C" void kernel_launch(void* const* d_in, const int* in_sizes, int n_in,
                              void* d_out, int out_size, void* d_ws, size_t ws_size,
                              hipStream_t stream) {
  const float* xpad   = (const float*)d_in[0];
  const float* W_ih0  = (const float*)d_in[1];
  const float* W_ihr  = (const float*)d_in[2];
  const float* W_hh   = (const float*)d_in[3];
  const float* b_ih   = (const float*)d_in[4];
  const float* b_hh   = (const float*)d_in[5];
  const float* W_last = (const float*)d_in[6];
  const float* b_last = (const float*)d_in[7];
  const int*   ilens  = (const int*)d_in[8];

  char* ws = (char*)d_ws;
  u16* XG    = (u16*)(ws);                    // 67,108,864 B
  u16* YS0   = (u16*)(ws + 67108864);         // 16,777,216 B
  u16* YS1   = (u16*)(ws + 83886080);         // 16,777,216 B
  u16* hbuf  = (u16*)(ws + 100663296);        // 2*16*1024 bf16 = 65,536 B
  int* flags = (int*)(ws + 100728832);        // 64*16 ints = 4,096 B
  const size_t barrier_bytes = 65536 + 4096;  // hbuf+flags contiguous

  float* out = (float*)d_out;

  dim3 blk(256);
  dim3 gXG(MROWS / 64, GD / 64);
  dim3 gFin(MROWS / 64, HD / 64);

  // ---- layer 0 ----
  gemm64<ID, false, false, false, true><<<gXG, blk, 0, stream>>>(
      xpad, W_ih0, b_ih, b_hh, XG, nullptr, GD);
  hipMemsetAsync(hbuf, 0, barrier_bytes, stream);
  rec_kernel<<<dim3(NWG), blk, 0, stream>>>(XG, W_hh, YS0, hbuf, flags);

  // ---- layer 1 ----
  gemm64<CD, true, false, false, true><<<gXG, blk, 0, stream>>>(
      YS0, W_ihr, b_ih + GD, b_hh + GD, XG, nullptr, GD);
  hipMemsetAsync(hbuf, 0, barrier_bytes, stream);
  rec_kernel<<<dim3(NWG), blk, 0, stream>>>(
      XG, W_hh + (size_t)GD * CD, YS1, hbuf, flags);

  // ---- layer 2 ----
  gemm64<CD, true, false, false, true><<<gXG, blk, 0, stream>>>(
      YS1, W_ihr + (size_t)GD * CD, b_ih + 2 * GD, b_hh + 2 * GD, XG, nullptr, GD);
  hipMemsetAsync(hbuf, 0, barrier_bytes, stream);
  rec_kernel<<<dim3(NWG), blk, 0, stream>>>(
      XG, W_hh + 2 * (size_t)GD * CD, YS0, hbuf, flags);

  // ---- layer 3 ----
  gemm64<CD, true, false, false, true><<<gXG, blk, 0, stream>>>(
      YS0, W_ihr + 2 * (size_t)GD * CD, b_ih + 3 * GD, b_hh + 3 * GD, XG, nullptr, GD);
  hipMemsetAsync(hbuf, 0, barrier_bytes, stream);
  rec_kernel<<<dim3(NWG), blk, 0, stream>>>(
      XG, W_hh + 3 * (size_t)GD * CD, YS1, hbuf, flags);

  // ---- masked tanh projection + ilens ----
  gemm64<CD, true, true, true, false><<<gFin, blk, 0, stream>>>(
      YS1, W_last, b_last, nullptr, out, ilens, HD);
  write_ilens_kernel<<<dim3(1), dim3(64), 0, stream>>>(out, ilens);
}

// Round 7
// 11170.291 us; speedup vs baseline: 4.6083x; 2.1056x over previous
//
#include <hip/hip_runtime.h>
#include <stdint.h>

#define T_STEPS 512
#define BATCH   16
#define CD      1024
#define GD      4096          // 4*CD
#define ID      320
#define HD      1024
#define MROWS   (BATCH*T_STEPS)   // 8192
#define NWG     64            // recurrence grid size
#define CPW     16            // channels per wg

typedef short bf16x8 __attribute__((ext_vector_type(8)));
typedef float f32x4  __attribute__((ext_vector_type(4)));
typedef int   i32x4  __attribute__((ext_vector_type(4)));
typedef unsigned short u16;
typedef unsigned long long u64;

__device__ __forceinline__ u16 f2bf(float f) {
  union { float f; uint32_t u; } v; v.f = f;
  uint32_t r = v.u + 0x7FFFu + ((v.u >> 16) & 1u);
  return (u16)(r >> 16);
}
__device__ __forceinline__ float bf2f(u16 u) {
  union { uint32_t u; float f; } v; v.u = ((uint32_t)u) << 16;
  return v.f;
}
__device__ __forceinline__ float sigm(float x) { return 1.0f / (1.0f + __expf(-x)); }

// ---------------------------------------------------------------------------
// Tiled bf16-MFMA GEMM (unchanged — verified passing).
// ---------------------------------------------------------------------------
template<int K, bool A_BF16, bool MASK_A, bool TANH_OUT, bool OUT_BF16>
__global__ __launch_bounds__(256)
void gemm64(const void* __restrict__ Av, const float* __restrict__ B,
            const float* __restrict__ bias1, const float* __restrict__ bias2,
            void* __restrict__ Outv, const int* __restrict__ ilens, int N) {
  const int m0 = blockIdx.x * 64;
  const int n0 = blockIdx.y * 64;
  const int tid = threadIdx.x;
  const int lane = tid & 63, wid = tid >> 6;
  const int wm = wid >> 1, wn = wid & 1;
  __shared__ u16 As[64][72];
  __shared__ u16 Bs[64][72];
  f32x4 acc[2][2];
  #pragma unroll
  for (int i = 0; i < 2; i++)
    #pragma unroll
    for (int j = 0; j < 2; j++) acc[i][j] = (f32x4){0.f,0.f,0.f,0.f};

  for (int k0 = 0; k0 < K; k0 += 64) {
    if constexpr (A_BF16) {
      const u16* A = (const u16*)Av;
      #pragma unroll
      for (int i = 0; i < 2; i++) {
        int idx = tid + i * 256;
        int row = idx >> 3, c8 = (idx & 7) * 8;
        int m = m0 + row;
        bf16x8 v = *(const bf16x8*)(A + (size_t)m * K + k0 + c8);
        if constexpr (MASK_A) {
          int tt = m & (T_STEPS - 1), b = m >> 9;
          if (tt >= ilens[b]) v = (bf16x8){0,0,0,0,0,0,0,0};
        }
        *(bf16x8*)&As[row][c8] = v;
      }
    } else {
      const float* A = (const float*)Av;
      #pragma unroll
      for (int i = 0; i < 4; i++) {
        int idx = tid + i * 256;
        int row = idx >> 4, c4 = (idx & 15) * 4;
        const float4 v = *(const float4*)(A + (size_t)(m0 + row) * K + k0 + c4);
        As[row][c4+0] = f2bf(v.x); As[row][c4+1] = f2bf(v.y);
        As[row][c4+2] = f2bf(v.z); As[row][c4+3] = f2bf(v.w);
      }
    }
    #pragma unroll
    for (int i = 0; i < 4; i++) {
      int idx = tid + i * 256;
      int row = idx >> 4, c4 = (idx & 15) * 4;
      const float4 v = *(const float4*)(B + (size_t)(n0 + row) * K + k0 + c4);
      Bs[row][c4+0] = f2bf(v.x); Bs[row][c4+1] = f2bf(v.y);
      Bs[row][c4+2] = f2bf(v.z); Bs[row][c4+3] = f2bf(v.w);
    }
    __syncthreads();
    const int rl = lane & 15;
    #pragma unroll
    for (int kk = 0; kk < 64; kk += 32) {
      const int kg = (lane >> 4) * 8 + kk;
      bf16x8 a[2], b[2];
      #pragma unroll
      for (int i = 0; i < 2; i++) a[i] = *(const bf16x8*)&As[wm*32 + i*16 + rl][kg];
      #pragma unroll
      for (int j = 0; j < 2; j++) b[j] = *(const bf16x8*)&Bs[wn*32 + j*16 + rl][kg];
      #pragma unroll
      for (int i = 0; i < 2; i++)
        #pragma unroll
        for (int j = 0; j < 2; j++)
          acc[i][j] = __builtin_amdgcn_mfma_f32_16x16x32_bf16(a[i], b[j], acc[i][j], 0, 0, 0);
    }
    __syncthreads();
  }
  const int rl = lane & 15, rg = lane >> 4;
  #pragma unroll
  for (int i = 0; i < 2; i++)
    #pragma unroll
    for (int j = 0; j < 2; j++) {
      int n = n0 + wn*32 + j*16 + rl;
      float bs = (bias1 ? bias1[n] : 0.f) + (bias2 ? bias2[n] : 0.f);
      #pragma unroll
      for (int r = 0; r < 4; r++) {
        int m = m0 + wm*32 + i*16 + rg*4 + r;
        float v = acc[i][j][r] + bs;
        if constexpr (TANH_OUT) v = tanhf(v);
        if constexpr (OUT_BF16) ((u16*)Outv)[(size_t)m * N + n] = f2bf(v);
        else                    ((float*)Outv)[(size_t)m * N + n] = v;
      }
    }
}

// ---------------------------------------------------------------------------
// Persistent LSTM recurrence, v3: 64 wgs x 256 threads (4 waves).
// W_hh A-fragments live in REGISTERS (128 VGPR/lane, loop-invariant).
// h exchanged per step: coalesced 16B coherent loads (sc0 sc1, L1/L2 bypass)
// -> swizzled LDS -> ds_read_b128 B-fragments. 16K line-requests/step
// device-wide vs 1M 8B atomic requests in v2.
// Barrier: 64 flags, wave 0 lane l polls wg l; one release store per wg/step.
// ---------------------------------------------------------------------------
__global__ __launch_bounds__(256, 1)
void rec_kernel(const u16* __restrict__ XG, const float* __restrict__ Whh,
                u16* __restrict__ YS, u16* hbuf, int* flags) {
  const int wg  = blockIdx.x;        // 0..63
  const int tid = threadIdx.x;       // 0..255
  const int lane = tid & 63;
  const int g    = tid >> 6;         // wave index = gate index
  const int ch0  = wg * CPW;

  __shared__ u16  Hh[16][1024];      // h bf16, elem c of row b at c ^ ((b&7)<<3)
  __shared__ float P[64][17];        // P[gate*16+ch][b]
  __shared__ u16  Hpack[16][16];     // new h bf16 [b][ch]

  const int rm  = lane & 15;                 // W-row within wave / batch col
  const int kg8 = (lane >> 4) * 8;           // k-group
  const int xk  = (rm & 7) << 3;             // swizzle key
  const int b_  = tid >> 4, c_ = tid & 15;   // elementwise owner (b, ch)
  const int srow0 = tid >> 7;                // staging row parity
  const int scol  = (tid * 8) & 1023;        // staging col (elements)

  // ---- A-fragments: W_hh row (g*CD + ch0 + rm), f32 -> bf16, into regs ----
  bf16x8 wreg[32];
  {
    const float* wrow = Whh + ((size_t)g * CD + ch0 + rm) * CD;
    #pragma unroll
    for (int ks = 0; ks < 32; ++ks) {
      float4 lo = *(const float4*)(wrow + ks * 32 + kg8);
      float4 hi = *(const float4*)(wrow + ks * 32 + kg8 + 4);
      bf16x8 w;
      w[0]=f2bf(lo.x); w[1]=f2bf(lo.y); w[2]=f2bf(lo.z); w[3]=f2bf(lo.w);
      w[4]=f2bf(hi.x); w[5]=f2bf(hi.y); w[6]=f2bf(hi.z); w[7]=f2bf(hi.w);
      wreg[ks] = w;
    }
  }

  float c_state = 0.f;

  // xg prefetch (t=0)
  const u16* xgp = XG + ((size_t)b_ * T_STEPS) * GD + ch0 + c_;
  float xn0 = bf2f(xgp[0]), xn1 = bf2f(xgp[CD]),
        xn2 = bf2f(xgp[2*CD]), xn3 = bf2f(xgp[3*CD]);

  int cur = 0;
  for (int t = 0; t < T_STEPS; ++t) {
    // ---- stage h[cur] -> LDS: 8x coherent dwordx4 per thread, coalesced ----
    {
      const u16* hsrc = hbuf + (size_t)cur * (BATCH * CD) + tid * 8;
      i32x4 hv[8];
      #pragma unroll
      for (int r = 0; r < 8; ++r) {
        const u16* p = hsrc + r * 2048;
        asm volatile("global_load_dwordx4 %0, %1, off sc0 sc1"
                     : "=v"(hv[r]) : "v"(p));
      }
      asm volatile("s_waitcnt vmcnt(0)" ::: "memory");
      __builtin_amdgcn_sched_barrier(0);
      #pragma unroll
      for (int r = 0; r < 8; ++r) {
        int row = srow0 + 2 * r;
        *(i32x4*)&Hh[row][scol ^ ((row & 7) << 3)] = hv[r];
      }
    }
    __syncthreads();

    // ---- P[r][b] = sum_k W[r][k] * h[b][k] : 32 MFMAs, A from regs ----
    f32x4 acc0 = (f32x4){0.f,0.f,0.f,0.f}, acc1 = (f32x4){0.f,0.f,0.f,0.f};
    #pragma unroll
    for (int ks = 0; ks < 32; ks += 2) {
      bf16x8 b0 = *(const bf16x8*)&Hh[rm][(ks * 32 + kg8) ^ xk];
      bf16x8 b1 = *(const bf16x8*)&Hh[rm][((ks + 1) * 32 + kg8) ^ xk];
      acc0 = __builtin_amdgcn_mfma_f32_16x16x32_bf16(wreg[ks],     b0, acc0, 0, 0, 0);
      acc1 = __builtin_amdgcn_mfma_f32_16x16x32_bf16(wreg[ks + 1], b1, acc1, 0, 0, 0);
    }
    f32x4 acc = acc0 + acc1;
    #pragma unroll
    for (int r4 = 0; r4 < 4; ++r4)
      P[(g << 4) + ((lane >> 4) << 2) + r4][rm] = acc[r4];
    __syncthreads();

    // ---- gates + state update (thread owns (b_, c_)) ----
    float gi = xn0 + P[c_][b_];
    float gf = xn1 + P[16 + c_][b_];
    float gg = xn2 + P[32 + c_][b_];
    float go = xn3 + P[48 + c_][b_];
    if (t + 1 < T_STEPS) {
      const u16* p = xgp + (size_t)(t + 1) * GD;
      xn0 = bf2f(p[0]); xn1 = bf2f(p[CD]); xn2 = bf2f(p[2*CD]); xn3 = bf2f(p[3*CD]);
    }
    c_state = sigm(gf) * c_state + sigm(gi) * tanhf(gg);
    float hv = sigm(go) * tanhf(c_state);
    Hpack[b_][c_] = f2bf(hv);
    __syncthreads();

    // ---- wave 0: publish h (agent stores), YS, flag release, poll ----
    if (tid < 64) {
      int bb = tid >> 2, q = tid & 3;
      u64 hw = *(const u64*)&Hpack[bb][q * 4];
      __hip_atomic_store((u64*)(hbuf + (size_t)(cur ^ 1) * (BATCH*CD) + bb * CD + ch0 + q * 4),
                         hw, __ATOMIC_RELAXED, __HIP_MEMORY_SCOPE_AGENT);
      *(u64*)(YS + ((size_t)bb * T_STEPS + t) * CD + ch0 + q * 4) = hw;
      if (t + 1 < T_STEPS) {
        if (tid == 0)   // release: wave-wide vmcnt(0) drain precedes flag store
          __hip_atomic_store(&flags[wg * 16], t + 1, __ATOMIC_RELEASE, __HIP_MEMORY_SCOPE_AGENT);
        while (__hip_atomic_load(&flags[tid * 16], __ATOMIC_RELAXED, __HIP_MEMORY_SCOPE_AGENT) < t + 1)
          __builtin_amdgcn_s_sleep(1);
        asm volatile("" ::: "memory");
      }
    }
    __syncthreads();
    cur ^= 1;
  }
}

__global__ void write_ilens_kernel(float* out, const int* ilens) {
  if (threadIdx.x < BATCH)
    out[(size_t)MROWS * HD + threadIdx.x] = (float)ilens[threadIdx.x];
}

// ---------------------------------------------------------------------------
extern "C" void kernel_launch(void* const* d_in, const int* in_sizes, int n_in,
                              void* d_out, int out_size, void* d_ws, size_t ws_size,
                              hipStream_t stream) {
  const float* xpad   = (const float*)d_in[0];
  const float* W_ih0  = (const float*)d_in[1];
  const float* W_ihr  = (const float*)d_in[2];
  const float* W_hh   = (const float*)d_in[3];
  const float* b_ih   = (const float*)d_in[4];
  const float* b_hh   = (const float*)d_in[5];
  const float* W_last = (const float*)d_in[6];
  const float* b_last = (const float*)d_in[7];
  const int*   ilens  = (const int*)d_in[8];

  char* ws = (char*)d_ws;
  u16* XG    = (u16*)(ws);                    // 67,108,864 B
  u16* YS0   = (u16*)(ws + 67108864);         // 16,777,216 B
  u16* YS1   = (u16*)(ws + 83886080);         // 16,777,216 B
  u16* hbuf  = (u16*)(ws + 100663296);        // 2*16*1024 bf16 = 65,536 B
  int* flags = (int*)(ws + 100728832);        // 64*16 ints = 4,096 B
  const size_t barrier_bytes = 65536 + 4096;  // hbuf+flags contiguous

  float* out = (float*)d_out;

  dim3 blk(256);
  dim3 gXG(MROWS / 64, GD / 64);
  dim3 gFin(MROWS / 64, HD / 64);

  // ---- layer 0 ----
  gemm64<ID, false, false, false, true><<<gXG, blk, 0, stream>>>(
      xpad, W_ih0, b_ih, b_hh, XG, nullptr, GD);
  hipMemsetAsync(hbuf, 0, barrier_bytes, stream);
  rec_kernel<<<dim3(NWG), blk, 0, stream>>>(XG, W_hh, YS0, hbuf, flags);

  // ---- layer 1 ----
  gemm64<CD, true, false, false, true><<<gXG, blk, 0, stream>>>(
      YS0, W_ihr, b_ih + GD, b_hh + GD, XG, nullptr, GD);
  hipMemsetAsync(hbuf, 0, barrier_bytes, stream);
  rec_kernel<<<dim3(NWG), blk, 0, stream>>>(
      XG, W_hh + (size_t)GD * CD, YS1, hbuf, flags);

  // ---- layer 2 ----
  gemm64<CD, true, false, false, true><<<gXG, blk, 0, stream>>>(
      YS1, W_ihr + (size_t)GD * CD, b_ih + 2 * GD, b_hh + 2 * GD, XG, nullptr, GD);
  hipMemsetAsync(hbuf, 0, barrier_bytes, stream);
  rec_kernel<<<dim3(NWG), blk, 0, stream>>>(
      XG, W_hh + 2 * (size_t)GD * CD, YS0, hbuf, flags);

  // ---- layer 3 ----
  gemm64<CD, true, false, false, true><<<gXG, blk, 0, stream>>>(
      YS0, W_ihr + 2 * (size_t)GD * CD, b_ih + 3 * GD, b_hh + 3 * GD, XG, nullptr, GD);
  hipMemsetAsync(hbuf, 0, barrier_bytes, stream);
  rec_kernel<<<dim3(NWG), blk, 0, stream>>>(
      XG, W_hh + 3 * (size_t)GD * CD, YS1, hbuf, flags);

  // ---- masked tanh projection + ilens ----
  gemm64<CD, true, true, true, false><<<gFin, blk, 0, stream>>>(
      YS1, W_last, b_last, nullptr, out, ilens, HD);
  write_ilens_kernel<<<dim3(1), dim3(64), 0, stream>>>(out, ilens);
}